// Round 1
// baseline (286.199 us; speedup 1.0000x reference)
//
#include <hip/hip_runtime.h>

#define D_MODEL 128

// ---------------------------------------------------------------------------
// Edge-index normalization: accept either int32 or int64 on-device layout.
// Detection: first 8 entries read as int64 must all be in [0, 2^31) to be
// genuine int64 (int32 pairs re-read as int64 are ~always >= 2^32).
// ---------------------------------------------------------------------------
__global__ void cvt_edges_kernel(const void* __restrict__ ei,
                                 int* __restrict__ s32, int* __restrict__ d32, int nE) {
    const long long* p64 = (const long long*)ei;
    const int* p32 = (const int*)ei;
    bool f64 = true;
#pragma unroll
    for (int i = 0; i < 8; ++i) {
        long long v = p64[i];
        f64 = f64 && (v >= 0 && v < (1LL << 31));
    }
    int e = blockIdx.x * blockDim.x + threadIdx.x;
    if (e < nE) {
        if (f64) {
            s32[e] = (int)p64[e];
            d32[e] = (int)p64[(size_t)nE + e];
        } else {
            s32[e] = p32[e];
            d32[e] = p32[(size_t)nE + e];
        }
    }
}

// ---------------------------------------------------------------------------
// Degree histograms
// ---------------------------------------------------------------------------
__global__ void deg_kernel(const int* __restrict__ src, const int* __restrict__ dst,
                           int* __restrict__ deg_out, int* __restrict__ deg_in, int nE) {
    int e = blockIdx.x * blockDim.x + threadIdx.x;
    if (e < nE) {
        atomicAdd(&deg_out[src[e]], 1);
        atomicAdd(&deg_in[dst[e]], 1);
    }
}

// ---------------------------------------------------------------------------
// Single-block exclusive scan: offs[0]=0, offs[i+1]=sum(deg[0..i])
// ---------------------------------------------------------------------------
__global__ __launch_bounds__(1024) void scan_kernel(const int* __restrict__ deg,
                                                    int* __restrict__ offs, int n) {
    __shared__ int warp_sums[16];
    __shared__ int carry_s;
    int tid = threadIdx.x;
    int lane = tid & 63;
    int wid = tid >> 6;
    if (tid == 0) carry_s = 0;
    __syncthreads();
    for (int base = 0; base < n; base += 1024) {
        int i = base + tid;
        int v = (i < n) ? deg[i] : 0;
        int s = v;
#pragma unroll
        for (int d = 1; d < 64; d <<= 1) {
            int t = __shfl_up(s, d, 64);
            if (lane >= d) s += t;
        }
        if (lane == 63) warp_sums[wid] = s;
        __syncthreads();
        if (wid == 0) {
            int wsv = (lane < 16) ? warp_sums[lane] : 0;
#pragma unroll
            for (int d = 1; d < 16; d <<= 1) {
                int t = __shfl_up(wsv, d, 16);
                if ((lane & 15) >= d) wsv += t;
            }
            if (lane < 16) warp_sums[lane] = wsv;
        }
        __syncthreads();
        int carry = carry_s;
        int wprefix = (wid > 0) ? warp_sums[wid - 1] : 0;
        if (i < n) offs[i + 1] = carry + wprefix + s;
        __syncthreads();
        if (tid == 0) carry_s = carry + warp_sums[15];
        __syncthreads();
    }
    if (tid == 0) offs[0] = 0;
}

// ---------------------------------------------------------------------------
// Fill CSR (sorted by dst), with per-edge symmetric norm precomputed
// ---------------------------------------------------------------------------
__global__ void fill_kernel(const int* __restrict__ src, const int* __restrict__ dst,
                            const int* __restrict__ deg_out, const int* __restrict__ deg_in,
                            const int* __restrict__ offs, int* __restrict__ cursor,
                            int* __restrict__ csr_src, float* __restrict__ csr_norm, int nE) {
    int e = blockIdx.x * blockDim.x + threadIdx.x;
    if (e >= nE) return;
    int s = src[e];
    int d = dst[e];
    int slot = offs[d] + atomicAdd(&cursor[d], 1);
    csr_src[slot] = s;
    csr_norm[slot] = rsqrtf(fmaxf((float)deg_out[s] * (float)deg_in[d], 1.0f));
}

// ---------------------------------------------------------------------------
// fp32 GEMM: M[N x 128] = A[N x 128] @ W[128 x 128]
// 256 threads/block, 32 rows/block, 4x4 register blocking per thread.
// ---------------------------------------------------------------------------
__global__ __launch_bounds__(256) void gemm_kernel(const float* __restrict__ A,
                                                   const float* __restrict__ W,
                                                   float* __restrict__ M, int nRows) {
    __shared__ float Ws[32][128];   // W rows k0..k0+31, all 128 cols
    __shared__ float At[32][36];    // A chunk transposed: At[kk][r]
    int tid = threadIdx.x;
    int tc = tid & 31;   // col group: cols 4*tc..4*tc+3
    int tr = tid >> 5;   // row group: rows 4*tr..4*tr+3
    int row0 = blockIdx.x * 32;
    float acc[4][4] = {};

    for (int k0 = 0; k0 < D_MODEL; k0 += 32) {
        __syncthreads();
        {
            const float4* Wg = (const float4*)(W + (size_t)k0 * D_MODEL);
            float4* WsV = (float4*)&Ws[0][0];
#pragma unroll
            for (int i = 0; i < 4; ++i) WsV[tid + 256 * i] = Wg[tid + 256 * i];
        }
#pragma unroll
        for (int i = 0; i < 4; ++i) {
            int lin = tid + 256 * i;   // 0..1023
            int r = lin >> 5;          // 0..31
            int kk = lin & 31;
            int row = row0 + r;
            At[kk][r] = (row < nRows) ? A[(size_t)row * D_MODEL + k0 + kk] : 0.0f;
        }
        __syncthreads();
#pragma unroll
        for (int kk = 0; kk < 32; ++kk) {
            float4 w4 = *(const float4*)&Ws[kk][4 * tc];
            float4 a4 = *(const float4*)&At[kk][4 * tr];
            float wv[4] = {w4.x, w4.y, w4.z, w4.w};
            float av[4] = {a4.x, a4.y, a4.z, a4.w};
#pragma unroll
            for (int i = 0; i < 4; ++i)
#pragma unroll
                for (int j = 0; j < 4; ++j)
                    acc[i][j] = fmaf(av[i], wv[j], acc[i][j]);
        }
    }
#pragma unroll
    for (int i = 0; i < 4; ++i) {
        int row = row0 + 4 * tr + i;
        if (row < nRows) {
            float4 o = {acc[i][0], acc[i][1], acc[i][2], acc[i][3]};
            *(float4*)(M + (size_t)row * D_MODEL + 4 * tc) = o;
        }
    }
}

// ---------------------------------------------------------------------------
// Per-node aggregation: one wave per dst node, lane owns 2 features (float2).
// h[v] = sum_e norm[e] * m[src[e]] + bias
// ---------------------------------------------------------------------------
__global__ __launch_bounds__(256) void agg_kernel(const float* __restrict__ m,
                                                  const int* __restrict__ offs,
                                                  const int* __restrict__ csr_src,
                                                  const float* __restrict__ csr_norm,
                                                  const float* __restrict__ bias,
                                                  float* __restrict__ hout, int n) {
    int gid = blockIdx.x * blockDim.x + threadIdx.x;
    int node = gid >> 6;
    int lane = threadIdx.x & 63;
    if (node >= n) return;
    node = __builtin_amdgcn_readfirstlane(node);  // wave-uniform -> scalar loads
    int beg = offs[node];
    int end = offs[node + 1];
    int off = 2 * lane;
    float ax = 0.0f, ay = 0.0f;
    for (int e = beg; e < end; ++e) {
        int s = csr_src[e];
        float nm = csr_norm[e];
        float2 v = *(const float2*)(m + (size_t)s * D_MODEL + off);
        ax = fmaf(nm, v.x, ax);
        ay = fmaf(nm, v.y, ay);
    }
    float2 bb = *(const float2*)(bias + off);
    float2 o = {ax + bb.x, ay + bb.y};
    *(float2*)(hout + (size_t)node * D_MODEL + off) = o;
}

// ---------------------------------------------------------------------------
// Fallback path (small ws): bias-init + edge-parallel fp32 atomics
// ---------------------------------------------------------------------------
__global__ void bias_init_kernel(const float* __restrict__ bias, float* __restrict__ hout, int n) {
    int gid = blockIdx.x * blockDim.x + threadIdx.x;
    if (gid < n * D_MODEL) hout[gid] = bias[gid & (D_MODEL - 1)];
}

__global__ __launch_bounds__(256) void agg_atomic_kernel(const float* __restrict__ m,
                                                         const int* __restrict__ src,
                                                         const int* __restrict__ dst,
                                                         const int* __restrict__ deg_out,
                                                         const int* __restrict__ deg_in,
                                                         float* __restrict__ hout, int nE) {
    int gid = blockIdx.x * blockDim.x + threadIdx.x;
    int e = gid >> 6;
    int lane = threadIdx.x & 63;
    if (e >= nE) return;
    int s = src[e], d = dst[e];
    float nm = rsqrtf(fmaxf((float)deg_out[s] * (float)deg_in[d], 1.0f));
    int off = 2 * lane;
    float2 v = *(const float2*)(m + (size_t)s * D_MODEL + off);
    atomicAdd(&hout[(size_t)d * D_MODEL + off], nm * v.x);
    atomicAdd(&hout[(size_t)d * D_MODEL + off + 1], nm * v.y);
}

// ---------------------------------------------------------------------------
extern "C" void kernel_launch(void* const* d_in, const int* in_sizes, int n_in,
                              void* d_out, int out_size, void* d_ws, size_t ws_size,
                              hipStream_t stream) {
    const float* x = (const float*)d_in[0];
    const float* W = (const float*)d_in[1];
    const float* b = (const float*)d_in[2];
    const void* ei = d_in[3];
    const int D = D_MODEL;
    int N = in_sizes[0] / D;
    int L = in_sizes[1] / (D * D);
    int E = in_sizes[3] / 2;
    float* out = (float*)d_out;

    char* p = (char*)d_ws;
    size_t off = 0;
    auto take = [&](size_t bytes) {
        void* r = p + off;
        off += (bytes + 255) & ~(size_t)255;
        return r;
    };
    int* deg_out  = (int*)take((size_t)N * 4);
    int* deg_in   = (int*)take((size_t)N * 4);
    int* s32      = (int*)take((size_t)E * 4);
    int* d32      = (int*)take((size_t)E * 4);
    float* m      = (float*)take((size_t)N * D * 4);
    int* offs     = (int*)take((size_t)(N + 1) * 4);
    int* cursor   = (int*)take((size_t)N * 4);
    int* csr_src  = (int*)take((size_t)E * 4);
    float* csr_norm = (float*)take((size_t)E * 4);
    size_t csr_need = off;

    int eb = (E + 255) / 256;
    cvt_edges_kernel<<<eb, 256, 0, stream>>>(ei, s32, d32, E);
    hipMemsetAsync(deg_out, 0, (size_t)N * 4, stream);
    hipMemsetAsync(deg_in, 0, (size_t)N * 4, stream);
    deg_kernel<<<eb, 256, 0, stream>>>(s32, d32, deg_out, deg_in, E);

    bool use_csr = (ws_size >= csr_need);
    if (use_csr) {
        hipMemsetAsync(cursor, 0, (size_t)N * 4, stream);
        scan_kernel<<<1, 1024, 0, stream>>>(deg_in, offs, N);
        fill_kernel<<<eb, 256, 0, stream>>>(s32, d32, deg_out, deg_in, offs, cursor,
                                            csr_src, csr_norm, E);
    }

    const float* h = x;
    for (int l = 0; l < L; ++l) {
        gemm_kernel<<<(N + 31) / 32, 256, 0, stream>>>(h, W + (size_t)l * D * D, m, N);
        if (use_csr) {
            agg_kernel<<<(N + 3) / 4, 256, 0, stream>>>(m, offs, csr_src, csr_norm,
                                                        b + (size_t)l * D, out, N);
        } else {
            bias_init_kernel<<<((size_t)N * D + 255) / 256, 256, 0, stream>>>(b + (size_t)l * D, out, N);
            agg_atomic_kernel<<<((size_t)E * 64 + 255) / 256, 256, 0, stream>>>(
                m, s32, d32, deg_out, deg_in, out, E);
        }
        h = out;
    }
}

// Round 2
// 202.709 us; speedup vs baseline: 1.4119x; 1.4119x over previous
//
#include <hip/hip_runtime.h>
#include <hip/hip_fp16.h>

#define D_MODEL 128
#define NREP 8

// ---------------------------------------------------------------------------
// Device-side edge dtype sniff: first 8 entries as int64 all in [0,2^31)
// => genuine int64; else int32 pairs.
// ---------------------------------------------------------------------------
__device__ __forceinline__ bool sniff_i64(const void* ei) {
    const long long* p64 = (const long long*)ei;
    bool f64 = true;
#pragma unroll
    for (int i = 0; i < 8; ++i) {
        long long v = p64[i];
        f64 = f64 && (v >= 0 && v < (1LL << 31));
    }
    return f64;
}

__device__ __forceinline__ void load_edge(const void* ei, int e, int nE, bool f64,
                                          int& s, int& d) {
    if (f64) {
        const long long* p64 = (const long long*)ei;
        s = (int)p64[e];
        d = (int)p64[(size_t)nE + e];
    } else {
        const int* p32 = (const int*)ei;
        s = p32[e];
        d = p32[(size_t)nE + e];
    }
}

// ---------------------------------------------------------------------------
// Degree histograms with 8-way replication (cut per-line atomic contention)
// ---------------------------------------------------------------------------
__global__ void prep_kernel(const void* __restrict__ ei, int* __restrict__ rep_out,
                            int* __restrict__ rep_in, int nE, int n) {
    bool f64 = sniff_i64(ei);
    int e = blockIdx.x * blockDim.x + threadIdx.x;
    if (e >= nE) return;
    int s, d;
    load_edge(ei, e, nE, f64, s, d);
    int rep = blockIdx.x & (NREP - 1);
    atomicAdd(&rep_out[(size_t)rep * n + s], 1);
    atomicAdd(&rep_in[(size_t)rep * n + d], 1);
}

// rep arrays -> a = rsqrt(deg_out), bfac = rsqrt(deg_in), ab = a*b, deg_in int
__global__ void deg_reduce_kernel(const int* __restrict__ rep_out,
                                  const int* __restrict__ rep_in,
                                  float* __restrict__ a, float* __restrict__ bfac,
                                  float* __restrict__ ab, int* __restrict__ deg_in,
                                  int n) {
    int v = blockIdx.x * blockDim.x + threadIdx.x;
    if (v >= n) return;
    int dout = 0, din = 0;
#pragma unroll
    for (int r = 0; r < NREP; ++r) {
        dout += rep_out[(size_t)r * n + v];
        din += rep_in[(size_t)r * n + v];
    }
    float fa = rsqrtf((float)max(dout, 1));
    float fb = rsqrtf((float)max(din, 1));
    a[v] = fa;
    bfac[v] = fb;
    ab[v] = fa * fb;
    deg_in[v] = din;
}

// ---------------------------------------------------------------------------
// 3-phase exclusive scan of deg_in -> offs[0..n], offs[n] = E
// ---------------------------------------------------------------------------
__global__ __launch_bounds__(1024) void scanA_kernel(const int* __restrict__ deg,
                                                     int* __restrict__ part, int n) {
    __shared__ int wsum[16];
    int i = blockIdx.x * 1024 + threadIdx.x;
    int lane = threadIdx.x & 63, wid = threadIdx.x >> 6;
    int v = (i < n) ? deg[i] : 0;
#pragma unroll
    for (int d = 32; d > 0; d >>= 1) v += __shfl_down(v, d, 64);
    if (lane == 0) wsum[wid] = v;
    __syncthreads();
    if (threadIdx.x == 0) {
        int s = 0;
#pragma unroll
        for (int w = 0; w < 16; ++w) s += wsum[w];
        part[blockIdx.x] = s;
    }
}

__global__ void scanB_kernel(const int* __restrict__ part, int* __restrict__ partx, int g) {
    if (blockIdx.x == 0 && threadIdx.x == 0) {
        int acc = 0;
        for (int i = 0; i < g; ++i) {
            partx[i] = acc;
            acc += part[i];
        }
    }
}

__global__ __launch_bounds__(1024) void scanC_kernel(const int* __restrict__ deg,
                                                     const int* __restrict__ partx,
                                                     int* __restrict__ offs, int n) {
    __shared__ int wsum[16];
    int i = blockIdx.x * 1024 + threadIdx.x;
    int lane = threadIdx.x & 63, wid = threadIdx.x >> 6;
    int v = (i < n) ? deg[i] : 0;
    int s = v;
#pragma unroll
    for (int d = 1; d < 64; d <<= 1) {
        int t = __shfl_up(s, d, 64);
        if (lane >= d) s += t;
    }
    if (lane == 63) wsum[wid] = s;
    __syncthreads();
    if (wid == 0) {
        int wsv = (lane < 16) ? wsum[lane] : 0;
#pragma unroll
        for (int d = 1; d < 16; d <<= 1) {
            int t = __shfl_up(wsv, d, 16);
            if ((lane & 15) >= d) wsv += t;
        }
        if (lane < 16) wsum[lane] = wsv;
    }
    __syncthreads();
    int base = partx[blockIdx.x] + ((wid > 0) ? wsum[wid - 1] : 0);
    int incl = base + s;
    if (i < n) {
        offs[i] = incl - v;           // exclusive
        if (i == n - 1) offs[n] = incl;
    }
}

// ---------------------------------------------------------------------------
// CSR fill (src only; norms are factorized into per-node a/b)
// ---------------------------------------------------------------------------
__global__ void fill_kernel(const void* __restrict__ ei, const int* __restrict__ offs,
                            int* __restrict__ cursor, int* __restrict__ csr_src, int nE) {
    bool f64 = sniff_i64(ei);
    int e = blockIdx.x * blockDim.x + threadIdx.x;
    if (e >= nE) return;
    int s, d;
    load_edge(ei, e, nE, f64, s, d);
    int slot = offs[d] + atomicAdd(&cursor[d], 1);
    csr_src[slot] = s;
}

// ---------------------------------------------------------------------------
// x' = fp16(a[row] * x)   (row-scaled, half precision for gather)
// ---------------------------------------------------------------------------
__global__ void xcvt_kernel(const float* __restrict__ x, const float* __restrict__ a,
                            float2* __restrict__ xh, int n4) {
    int idx = blockIdx.x * blockDim.x + threadIdx.x;
    if (idx >= n4) return;
    int row = idx >> 5;   // 32 float4 per row
    float s = a[row];
    float4 v = ((const float4*)x)[idx];
    union { __half2 h2[2]; float2 f2; } u;
    u.h2[0] = __floats2half2_rn(s * v.x, s * v.y);
    u.h2[1] = __floats2half2_rn(s * v.z, s * v.w);
    xh[idx] = u.f2;
}

// ---------------------------------------------------------------------------
// Gather-sum aggregation over fp16 rows. One wave per dst node, lane owns
// half2 (2 features). MODE 0: out = fp16(ab[v] * sum)   (feeds next gather)
// MODE 1: out = fp16(sum) raw, plus c[v] = bfac[v] * sum(a[src])
// ---------------------------------------------------------------------------
template <int MODE>
__global__ __launch_bounds__(256) void agg_kernel(const __half2* __restrict__ rows_in,
                                                  const int* __restrict__ offs,
                                                  const int* __restrict__ csr,
                                                  const float* __restrict__ ab,
                                                  const float* __restrict__ bfac,
                                                  const float* __restrict__ a_arr,
                                                  __half2* __restrict__ out_rows,
                                                  float* __restrict__ c_out, int n) {
    int node = blockIdx.x * 4 + (threadIdx.x >> 6);
    if (node >= n) return;
    node = __builtin_amdgcn_readfirstlane(node);
    int lane = threadIdx.x & 63;
    int beg = offs[node], end = offs[node + 1];
    float ax0 = 0.f, ay0 = 0.f, ax1 = 0.f, ay1 = 0.f;
    float cs = 0.f;
    int e = beg;
    for (; e + 1 < end; e += 2) {
        int s0 = csr[e], s1 = csr[e + 1];
        __half2 v0 = rows_in[(size_t)s0 * 64 + lane];
        __half2 v1 = rows_in[(size_t)s1 * 64 + lane];
        float2 f0 = __half22float2(v0);
        float2 f1 = __half22float2(v1);
        ax0 += f0.x; ay0 += f0.y;
        ax1 += f1.x; ay1 += f1.y;
        if (MODE == 1) cs += a_arr[s0] + a_arr[s1];
    }
    if (e < end) {
        int s0 = csr[e];
        __half2 v0 = rows_in[(size_t)s0 * 64 + lane];
        float2 f0 = __half22float2(v0);
        ax0 += f0.x; ay0 += f0.y;
        if (MODE == 1) cs += a_arr[s0];
    }
    float sx = ax0 + ax1, sy = ay0 + ay1;
    if (MODE == 0) {
        float sc = ab[node];
        out_rows[(size_t)node * 64 + lane] = __floats2half2_rn(sc * sx, sc * sy);
    } else {
        out_rows[(size_t)node * 64 + lane] = __floats2half2_rn(sx, sy);
        if (lane == 0) c_out[node] = bfac[node] * cs;
    }
}

// ---------------------------------------------------------------------------
// Combined weights: wc[0..127][128] = W1@W2 ; wc[128][:] = b1@W2
// ---------------------------------------------------------------------------
__global__ void wc_kernel(const float* __restrict__ W, const float* __restrict__ b,
                          float* __restrict__ wc) {
    int gid = blockIdx.x * blockDim.x + threadIdx.x;
    if (gid >= 129 * 128) return;
    int r = gid >> 7, j = gid & 127;
    const float* W2 = W + 128 * 128;
    float acc = 0.f;
    if (r < 128) {
        const float* w1r = W + (size_t)r * 128;
#pragma unroll 4
        for (int k = 0; k < 128; ++k) acc = fmaf(w1r[k], W2[(size_t)k * 128 + j], acc);
    } else {
#pragma unroll 4
        for (int k = 0; k < 128; ++k) acc = fmaf(b[k], W2[(size_t)k * 128 + j], acc);
    }
    wc[gid] = acc;
}

// ---------------------------------------------------------------------------
// Final GEMM + epilogue: out = bfac[row]*(t2raw @ Wc) + c[row]*g + b2
// t2raw is fp16 [N][128]; Wc fp32; 32 rows/block, 4x4 register blocking.
// ---------------------------------------------------------------------------
__global__ __launch_bounds__(256) void gemm_final_kernel(const __half2* __restrict__ A2,
                                                         const float* __restrict__ wc,
                                                         const float* __restrict__ bfac,
                                                         const float* __restrict__ c_arr,
                                                         const float* __restrict__ b2,
                                                         float* __restrict__ out, int nRows) {
    __shared__ float Ws[32][128];
    __shared__ float At[32][36];
    int tid = threadIdx.x;
    int tc = tid & 31;
    int tr = tid >> 5;
    int row0 = blockIdx.x * 32;
    float acc[4][4] = {};

    for (int k0 = 0; k0 < D_MODEL; k0 += 32) {
        __syncthreads();
        {
            const float4* Wg = (const float4*)(wc + (size_t)k0 * D_MODEL);
            float4* WsV = (float4*)&Ws[0][0];
#pragma unroll
            for (int i = 0; i < 4; ++i) WsV[tid + 256 * i] = Wg[tid + 256 * i];
        }
        int k0h = k0 >> 1;
#pragma unroll
        for (int i = 0; i < 2; ++i) {
            int lin = tid + 256 * i;      // 0..511
            int r = lin >> 4;             // 0..31
            int h = lin & 15;             // half2 index within 32-k chunk
            int row = row0 + r;
            __half2 v = (row < nRows) ? A2[(size_t)row * 64 + k0h + h]
                                      : __floats2half2_rn(0.f, 0.f);
            float2 f = __half22float2(v);
            At[2 * h][r] = f.x;
            At[2 * h + 1][r] = f.y;
        }
        __syncthreads();
#pragma unroll
        for (int kk = 0; kk < 32; ++kk) {
            float4 w4 = *(const float4*)&Ws[kk][4 * tc];
            float4 a4 = *(const float4*)&At[kk][4 * tr];
            float wv[4] = {w4.x, w4.y, w4.z, w4.w};
            float av[4] = {a4.x, a4.y, a4.z, a4.w};
#pragma unroll
            for (int i = 0; i < 4; ++i)
#pragma unroll
                for (int j = 0; j < 4; ++j)
                    acc[i][j] = fmaf(av[i], wv[j], acc[i][j]);
        }
    }
    float4 g4 = *(const float4*)(wc + 128 * 128 + 4 * tc);
    float4 b4 = *(const float4*)(b2 + 4 * tc);
#pragma unroll
    for (int i = 0; i < 4; ++i) {
        int row = row0 + 4 * tr + i;
        if (row < nRows) {
            float bf = bfac[row];
            float cv = c_arr[row];
            float4 o;
            o.x = bf * acc[i][0] + cv * g4.x + b4.x;
            o.y = bf * acc[i][1] + cv * g4.y + b4.y;
            o.z = bf * acc[i][2] + cv * g4.z + b4.z;
            o.w = bf * acc[i][3] + cv * g4.w + b4.w;
            *(float4*)(out + (size_t)row * D_MODEL + 4 * tc) = o;
        }
    }
}

// ---------------------------------------------------------------------------
extern "C" void kernel_launch(void* const* d_in, const int* in_sizes, int n_in,
                              void* d_out, int out_size, void* d_ws, size_t ws_size,
                              hipStream_t stream) {
    const float* x = (const float*)d_in[0];
    const float* W = (const float*)d_in[1];
    const float* b = (const float*)d_in[2];
    const void* ei = d_in[3];
    const int D = D_MODEL;
    int N = in_sizes[0] / D;
    int E = in_sizes[3] / 2;
    float* out = (float*)d_out;

    char* p = (char*)d_ws;
    size_t off = 0;
    auto take = [&](size_t bytes) {
        void* r = p + off;
        off += (bytes + 255) & ~(size_t)255;
        return r;
    };
    // region reused: x_half during aggregation 1, t2raw during aggregation 2+gemm
    __half2* xh   = (__half2*)take((size_t)N * D * 2);   // 10.24 MB (aliased as t2)
    __half2* u    = (__half2*)take((size_t)N * D * 2);   // 10.24 MB
    int* rep_out  = (int*)take((size_t)NREP * N * 4);    // 1.28 MB
    int* rep_in   = (int*)take((size_t)NREP * N * 4);    // 1.28 MB
    int* csr_src  = (int*)take((size_t)E * 4);           // 2.56 MB
    float* a_arr  = (float*)take((size_t)N * 4);
    float* bfac   = (float*)take((size_t)N * 4);
    float* ab     = (float*)take((size_t)N * 4);
    float* c_arr  = (float*)take((size_t)N * 4);
    int* deg_in   = (int*)take((size_t)N * 4);
    int* offs     = (int*)take((size_t)(N + 1) * 4);
    int* cursor   = (int*)take((size_t)N * 4);
    int* part     = (int*)take(256 * 4);
    int* partx    = (int*)take(256 * 4);
    float* wc     = (float*)take((size_t)129 * 128 * 4);
    __half2* t2   = xh;   // alias: x_half dead once agg<0> completes

    int eb = (E + 255) / 256;
    int G = (N + 1023) / 1024;

    hipMemsetAsync(rep_out, 0, (size_t)NREP * N * 4 * 2, stream);  // rep_out+rep_in contiguous
    hipMemsetAsync(cursor, 0, (size_t)N * 4, stream);

    wc_kernel<<<(129 * 128 + 255) / 256, 256, 0, stream>>>(W, b, wc);
    prep_kernel<<<eb, 256, 0, stream>>>(ei, rep_out, rep_in, E, N);
    deg_reduce_kernel<<<(N + 255) / 256, 256, 0, stream>>>(rep_out, rep_in, a_arr, bfac,
                                                           ab, deg_in, N);
    scanA_kernel<<<G, 1024, 0, stream>>>(deg_in, part, N);
    scanB_kernel<<<1, 64, 0, stream>>>(part, partx, G);
    scanC_kernel<<<G, 1024, 0, stream>>>(deg_in, partx, offs, N);
    fill_kernel<<<eb, 256, 0, stream>>>(ei, offs, cursor, csr_src, E);

    int n4 = N * (D / 4);
    xcvt_kernel<<<(n4 + 255) / 256, 256, 0, stream>>>(x, a_arr, (float2*)xh, n4);

    agg_kernel<0><<<(N + 3) / 4, 256, 0, stream>>>(xh, offs, csr_src, ab, bfac, a_arr,
                                                   u, c_arr, N);
    agg_kernel<1><<<(N + 3) / 4, 256, 0, stream>>>(u, offs, csr_src, ab, bfac, a_arr,
                                                   t2, c_arr, N);
    gemm_final_kernel<<<(N + 31) / 32, 256, 0, stream>>>(t2, wc, bfac, c_arr,
                                                         b + 128, out, N);
}

// Round 3
// 159.770 us; speedup vs baseline: 1.7913x; 1.2688x over previous
//
#include <hip/hip_runtime.h>
#include <hip/hip_fp16.h>

#define D_MODEL 128
#define NREP 8
#define FC 32   // edge-range chunks for LDS histogram / counting sort

// ---------------------------------------------------------------------------
// Device-side edge dtype sniff: first 8 entries as int64 all in [0,2^31)
// => genuine int64; else int32 pairs.
// ---------------------------------------------------------------------------
__device__ __forceinline__ bool sniff_i64(const void* ei) {
    const long long* p64 = (const long long*)ei;
    bool f64 = true;
#pragma unroll
    for (int i = 0; i < 8; ++i) {
        long long v = p64[i];
        f64 = f64 && (v >= 0 && v < (1LL << 31));
    }
    return f64;
}

__device__ __forceinline__ void load_edge(const void* ei, int e, int nE, bool f64,
                                          int& s, int& d) {
    if (f64) {
        const long long* p64 = (const long long*)ei;
        s = (int)p64[e];
        d = (int)p64[(size_t)nE + e];
    } else {
        const int* p32 = (const int*)ei;
        s = p32[e];
        d = p32[(size_t)nE + e];
    }
}

// ---------------------------------------------------------------------------
// LDS-histogram path: grid = 2*FC blocks; even blocks do src, odd do dst.
// Each block histograms its contiguous edge range into LDS (full N fits:
// 40000*4 = 156.25 KB < 160 KB), then flushes with plain stores.
// ---------------------------------------------------------------------------
__global__ __launch_bounds__(1024) void hist_kernel(const void* __restrict__ ei,
                                                    int* __restrict__ Cs,
                                                    int* __restrict__ Cd,
                                                    int nE, int n) {
    extern __shared__ int h[];
    bool f64 = sniff_i64(ei);
    int type = blockIdx.x & 1;        // 0 = src, 1 = dst
    int chunk = blockIdx.x >> 1;
    for (int i = threadIdx.x; i < n; i += 1024) h[i] = 0;
    __syncthreads();
    int ech = (nE + FC - 1) / FC;
    int e0 = chunk * ech;
    int e1 = min(nE, e0 + ech);
    size_t off = type ? (size_t)nE : 0;
    if (f64) {
        const long long* p64 = (const long long*)ei;
        for (int e = e0 + threadIdx.x; e < e1; e += 1024)
            atomicAdd(&h[(int)p64[off + e]], 1);
    } else {
        const int* p32 = (const int*)ei;
        for (int e = e0 + threadIdx.x; e < e1; e += 1024)
            atomicAdd(&h[p32[off + e]], 1);
    }
    __syncthreads();
    int* C = (type ? Cd : Cs) + (size_t)chunk * n;
    for (int i = threadIdx.x; i < n; i += 1024) C[i] = h[i];
}

// per-node factors from chunked histograms
__global__ void deg_reduce_kernel(const int* __restrict__ Cs,
                                  const int* __restrict__ Cd,
                                  float* __restrict__ a, float* __restrict__ bfac,
                                  float* __restrict__ ab, int* __restrict__ deg_in,
                                  int n) {
    int v = blockIdx.x * blockDim.x + threadIdx.x;
    if (v >= n) return;
    int dout = 0, din = 0;
#pragma unroll 8
    for (int c = 0; c < FC; ++c) {
        dout += Cs[(size_t)c * n + v];
        din += Cd[(size_t)c * n + v];
    }
    float fa = rsqrtf((float)max(dout, 1));
    float fb = rsqrtf((float)max(din, 1));
    a[v] = fa;
    bfac[v] = fb;
    ab[v] = fa * fb;
    deg_in[v] = din;
}

// ---------------------------------------------------------------------------
// Fallback path (N too big for LDS): global-atomic histograms
// ---------------------------------------------------------------------------
__global__ void prep_kernel(const void* __restrict__ ei, int* __restrict__ rep_out,
                            int* __restrict__ rep_in, int nE, int n) {
    bool f64 = sniff_i64(ei);
    int e = blockIdx.x * blockDim.x + threadIdx.x;
    if (e >= nE) return;
    int s, d;
    load_edge(ei, e, nE, f64, s, d);
    int rep = blockIdx.x & (NREP - 1);
    atomicAdd(&rep_out[(size_t)rep * n + s], 1);
    atomicAdd(&rep_in[(size_t)rep * n + d], 1);
}

__global__ void deg_reduce_rep_kernel(const int* __restrict__ rep_out,
                                      const int* __restrict__ rep_in,
                                      float* __restrict__ a, float* __restrict__ bfac,
                                      float* __restrict__ ab, int* __restrict__ deg_in,
                                      int n) {
    int v = blockIdx.x * blockDim.x + threadIdx.x;
    if (v >= n) return;
    int dout = 0, din = 0;
#pragma unroll
    for (int r = 0; r < NREP; ++r) {
        dout += rep_out[(size_t)r * n + v];
        din += rep_in[(size_t)r * n + v];
    }
    float fa = rsqrtf((float)max(dout, 1));
    float fb = rsqrtf((float)max(din, 1));
    a[v] = fa;
    bfac[v] = fb;
    ab[v] = fa * fb;
    deg_in[v] = din;
}

// ---------------------------------------------------------------------------
// 3-phase exclusive scan of deg_in -> offs[0..n]
// ---------------------------------------------------------------------------
__global__ __launch_bounds__(1024) void scanA_kernel(const int* __restrict__ deg,
                                                     int* __restrict__ part, int n) {
    __shared__ int wsum[16];
    int i = blockIdx.x * 1024 + threadIdx.x;
    int lane = threadIdx.x & 63, wid = threadIdx.x >> 6;
    int v = (i < n) ? deg[i] : 0;
#pragma unroll
    for (int d = 32; d > 0; d >>= 1) v += __shfl_down(v, d, 64);
    if (lane == 0) wsum[wid] = v;
    __syncthreads();
    if (threadIdx.x == 0) {
        int s = 0;
#pragma unroll
        for (int w = 0; w < 16; ++w) s += wsum[w];
        part[blockIdx.x] = s;
    }
}

__global__ void scanB_kernel(const int* __restrict__ part, int* __restrict__ partx, int g) {
    if (blockIdx.x == 0 && threadIdx.x == 0) {
        int acc = 0;
        for (int i = 0; i < g; ++i) {
            partx[i] = acc;
            acc += part[i];
        }
    }
}

__global__ __launch_bounds__(1024) void scanC_kernel(const int* __restrict__ deg,
                                                     const int* __restrict__ partx,
                                                     int* __restrict__ offs, int n) {
    __shared__ int wsum[16];
    int i = blockIdx.x * 1024 + threadIdx.x;
    int lane = threadIdx.x & 63, wid = threadIdx.x >> 6;
    int v = (i < n) ? deg[i] : 0;
    int s = v;
#pragma unroll
    for (int d = 1; d < 64; d <<= 1) {
        int t = __shfl_up(s, d, 64);
        if (lane >= d) s += t;
    }
    if (lane == 63) wsum[wid] = s;
    __syncthreads();
    if (wid == 0) {
        int wsv = (lane < 16) ? wsum[lane] : 0;
#pragma unroll
        for (int d = 1; d < 16; d <<= 1) {
            int t = __shfl_up(wsv, d, 16);
            if ((lane & 15) >= d) wsv += t;
        }
        if (lane < 16) wsum[lane] = wsv;
    }
    __syncthreads();
    int base = partx[blockIdx.x] + ((wid > 0) ? wsum[wid - 1] : 0);
    int incl = base + s;
    if (i < n) {
        offs[i] = incl - v;           // exclusive
        if (i == n - 1) offs[n] = incl;
    }
}

// ---------------------------------------------------------------------------
// Counting sort: absolute per-chunk cursors, then LDS-cursor fill
// ---------------------------------------------------------------------------
__global__ void base_kernel(const int* __restrict__ Cd, const int* __restrict__ offs,
                            int* __restrict__ base, int n) {
    int v = blockIdx.x * blockDim.x + threadIdx.x;
    if (v >= n) return;
    int run = offs[v];
#pragma unroll 8
    for (int c = 0; c < FC; ++c) {
        base[(size_t)c * n + v] = run;
        run += Cd[(size_t)c * n + v];
    }
}

__global__ __launch_bounds__(1024) void fill_lds_kernel(const void* __restrict__ ei,
                                                        const int* __restrict__ base,
                                                        int* __restrict__ csr_src,
                                                        int nE, int n) {
    extern __shared__ int cur[];
    bool f64 = sniff_i64(ei);
    int chunk = blockIdx.x;
    for (int i = threadIdx.x; i < n; i += 1024) cur[i] = base[(size_t)chunk * n + i];
    __syncthreads();
    int ech = (nE + FC - 1) / FC;
    int e0 = chunk * ech;
    int e1 = min(nE, e0 + ech);
    for (int e = e0 + threadIdx.x; e < e1; e += 1024) {
        int s, d;
        load_edge(ei, e, nE, f64, s, d);
        int slot = atomicAdd(&cur[d], 1);
        csr_src[slot] = s;
    }
}

// Fallback fill (global cursor atomics)
__global__ void fill_kernel(const void* __restrict__ ei, const int* __restrict__ offs,
                            int* __restrict__ cursor, int* __restrict__ csr_src, int nE) {
    bool f64 = sniff_i64(ei);
    int e = blockIdx.x * blockDim.x + threadIdx.x;
    if (e >= nE) return;
    int s, d;
    load_edge(ei, e, nE, f64, s, d);
    int slot = offs[d] + atomicAdd(&cursor[d], 1);
    csr_src[slot] = s;
}

// ---------------------------------------------------------------------------
// x' = fp16(a[row] * x)
// ---------------------------------------------------------------------------
__global__ void xcvt_kernel(const float* __restrict__ x, const float* __restrict__ a,
                            float2* __restrict__ xh, int n4) {
    int idx = blockIdx.x * blockDim.x + threadIdx.x;
    if (idx >= n4) return;
    int row = idx >> 5;   // 32 float4 per row
    float s = a[row];
    float4 v = ((const float4*)x)[idx];
    union { __half2 h2[2]; float2 f2; } u;
    u.h2[0] = __floats2half2_rn(s * v.x, s * v.y);
    u.h2[1] = __floats2half2_rn(s * v.z, s * v.w);
    xh[idx] = u.f2;
}

// ---------------------------------------------------------------------------
// Gather-sum aggregation over fp16 rows. One wave per dst node, lane owns
// half2. MODE 0: out = fp16(ab[v]*sum). MODE 1: out = fp16(sum), c[v] = b*sum(a[src]).
// ---------------------------------------------------------------------------
template <int MODE>
__global__ __launch_bounds__(256) void agg_kernel(const __half2* __restrict__ rows_in,
                                                  const int* __restrict__ offs,
                                                  const int* __restrict__ csr,
                                                  const float* __restrict__ ab,
                                                  const float* __restrict__ bfac,
                                                  const float* __restrict__ a_arr,
                                                  __half2* __restrict__ out_rows,
                                                  float* __restrict__ c_out, int n) {
    int node = blockIdx.x * 4 + (threadIdx.x >> 6);
    if (node >= n) return;
    node = __builtin_amdgcn_readfirstlane(node);
    int lane = threadIdx.x & 63;
    int beg = offs[node], end = offs[node + 1];
    float ax0 = 0.f, ay0 = 0.f, ax1 = 0.f, ay1 = 0.f;
    float cs = 0.f;
    int e = beg;
    for (; e + 1 < end; e += 2) {
        int s0 = csr[e], s1 = csr[e + 1];
        __half2 v0 = rows_in[(size_t)s0 * 64 + lane];
        __half2 v1 = rows_in[(size_t)s1 * 64 + lane];
        float2 f0 = __half22float2(v0);
        float2 f1 = __half22float2(v1);
        ax0 += f0.x; ay0 += f0.y;
        ax1 += f1.x; ay1 += f1.y;
        if (MODE == 1) cs += a_arr[s0] + a_arr[s1];
    }
    if (e < end) {
        int s0 = csr[e];
        __half2 v0 = rows_in[(size_t)s0 * 64 + lane];
        float2 f0 = __half22float2(v0);
        ax0 += f0.x; ay0 += f0.y;
        if (MODE == 1) cs += a_arr[s0];
    }
    float sx = ax0 + ax1, sy = ay0 + ay1;
    if (MODE == 0) {
        float sc = ab[node];
        out_rows[(size_t)node * 64 + lane] = __floats2half2_rn(sc * sx, sc * sy);
    } else {
        out_rows[(size_t)node * 64 + lane] = __floats2half2_rn(sx, sy);
        if (lane == 0) c_out[node] = bfac[node] * cs;
    }
}

// ---------------------------------------------------------------------------
// Combined weights: wc[0..127][128] = W1@W2 ; wc[128][:] = b1@W2
// ---------------------------------------------------------------------------
__global__ void wc_kernel(const float* __restrict__ W, const float* __restrict__ b,
                          float* __restrict__ wc) {
    int gid = blockIdx.x * blockDim.x + threadIdx.x;
    if (gid >= 129 * 128) return;
    int r = gid >> 7, j = gid & 127;
    const float* W2 = W + 128 * 128;
    float acc = 0.f;
    if (r < 128) {
        const float* w1r = W + (size_t)r * 128;
#pragma unroll 4
        for (int k = 0; k < 128; ++k) acc = fmaf(w1r[k], W2[(size_t)k * 128 + j], acc);
    } else {
#pragma unroll 4
        for (int k = 0; k < 128; ++k) acc = fmaf(b[k], W2[(size_t)k * 128 + j], acc);
    }
    wc[gid] = acc;
}

// ---------------------------------------------------------------------------
// Final GEMM + epilogue: out = bfac[row]*(t2raw @ Wc) + c[row]*g + b2
// ---------------------------------------------------------------------------
__global__ __launch_bounds__(256) void gemm_final_kernel(const __half2* __restrict__ A2,
                                                         const float* __restrict__ wc,
                                                         const float* __restrict__ bfac,
                                                         const float* __restrict__ c_arr,
                                                         const float* __restrict__ b2,
                                                         float* __restrict__ out, int nRows) {
    __shared__ float Ws[32][128];
    __shared__ float At[32][36];
    int tid = threadIdx.x;
    int tc = tid & 31;
    int tr = tid >> 5;
    int row0 = blockIdx.x * 32;
    float acc[4][4] = {};

    for (int k0 = 0; k0 < D_MODEL; k0 += 32) {
        __syncthreads();
        {
            const float4* Wg = (const float4*)(wc + (size_t)k0 * D_MODEL);
            float4* WsV = (float4*)&Ws[0][0];
#pragma unroll
            for (int i = 0; i < 4; ++i) WsV[tid + 256 * i] = Wg[tid + 256 * i];
        }
        int k0h = k0 >> 1;
#pragma unroll
        for (int i = 0; i < 2; ++i) {
            int lin = tid + 256 * i;      // 0..511
            int r = lin >> 4;             // 0..31
            int h = lin & 15;
            int row = row0 + r;
            __half2 v = (row < nRows) ? A2[(size_t)row * 64 + k0h + h]
                                      : __floats2half2_rn(0.f, 0.f);
            float2 f = __half22float2(v);
            At[2 * h][r] = f.x;
            At[2 * h + 1][r] = f.y;
        }
        __syncthreads();
#pragma unroll
        for (int kk = 0; kk < 32; ++kk) {
            float4 w4 = *(const float4*)&Ws[kk][4 * tc];
            float4 a4 = *(const float4*)&At[kk][4 * tr];
            float wv[4] = {w4.x, w4.y, w4.z, w4.w};
            float av[4] = {a4.x, a4.y, a4.z, a4.w};
#pragma unroll
            for (int i = 0; i < 4; ++i)
#pragma unroll
                for (int j = 0; j < 4; ++j)
                    acc[i][j] = fmaf(av[i], wv[j], acc[i][j]);
        }
    }
    float4 g4 = *(const float4*)(wc + 128 * 128 + 4 * tc);
    float4 b4 = *(const float4*)(b2 + 4 * tc);
#pragma unroll
    for (int i = 0; i < 4; ++i) {
        int row = row0 + 4 * tr + i;
        if (row < nRows) {
            float bf = bfac[row];
            float cv = c_arr[row];
            float4 o;
            o.x = bf * acc[i][0] + cv * g4.x + b4.x;
            o.y = bf * acc[i][1] + cv * g4.y + b4.y;
            o.z = bf * acc[i][2] + cv * g4.z + b4.z;
            o.w = bf * acc[i][3] + cv * g4.w + b4.w;
            *(float4*)(out + (size_t)row * D_MODEL + 4 * tc) = o;
        }
    }
}

// ---------------------------------------------------------------------------
extern "C" void kernel_launch(void* const* d_in, const int* in_sizes, int n_in,
                              void* d_out, int out_size, void* d_ws, size_t ws_size,
                              hipStream_t stream) {
    const float* x = (const float*)d_in[0];
    const float* W = (const float*)d_in[1];
    const float* b = (const float*)d_in[2];
    const void* ei = d_in[3];
    const int D = D_MODEL;
    int N = in_sizes[0] / D;
    int E = in_sizes[3] / 2;
    float* out = (float*)d_out;

    char* p = (char*)d_ws;
    size_t off = 0;
    auto take = [&](size_t bytes) {
        void* r = p + off;
        off += (bytes + 255) & ~(size_t)255;
        return r;
    };
    __half2* xh   = (__half2*)take((size_t)N * D * 2);
    __half2* u    = (__half2*)take((size_t)N * D * 2);
    int* csr_src  = (int*)take((size_t)E * 4);
    float* a_arr  = (float*)take((size_t)N * 4);
    float* bfac   = (float*)take((size_t)N * 4);
    float* ab     = (float*)take((size_t)N * 4);
    float* c_arr  = (float*)take((size_t)N * 4);
    int* deg_in   = (int*)take((size_t)N * 4);
    int* offs     = (int*)take((size_t)(N + 1) * 4);
    int* cursor   = (int*)take((size_t)N * 4);
    int* part     = (int*)take(256 * 4);
    int* partx    = (int*)take(256 * 4);
    float* wc     = (float*)take((size_t)129 * 128 * 4);
    size_t common = off;
    // LDS path tail: Cs, Cd, base
    int* Cs   = (int*)take((size_t)FC * N * 4);
    int* Cd   = (int*)take((size_t)FC * N * 4);
    int* base = (int*)take((size_t)FC * N * 4);
    size_t lds_need = off;
    __half2* t2 = xh;   // alias: x_half dead once agg<0> completes

    size_t lds_bytes = (size_t)N * 4;
    bool use_lds = (lds_bytes <= 160000) && (lds_need <= ws_size);

    int eb = (E + 255) / 256;
    int G = (N + 1023) / 1024;

    wc_kernel<<<(129 * 128 + 255) / 256, 256, 0, stream>>>(W, b, wc);

    if (use_lds) {
        hist_kernel<<<2 * FC, 1024, lds_bytes, stream>>>(ei, Cs, Cd, E, N);
        deg_reduce_kernel<<<(N + 255) / 256, 256, 0, stream>>>(Cs, Cd, a_arr, bfac,
                                                               ab, deg_in, N);
        scanA_kernel<<<G, 1024, 0, stream>>>(deg_in, part, N);
        scanB_kernel<<<1, 64, 0, stream>>>(part, partx, G);
        scanC_kernel<<<G, 1024, 0, stream>>>(deg_in, partx, offs, N);
        base_kernel<<<(N + 255) / 256, 256, 0, stream>>>(Cd, offs, base, N);
        fill_lds_kernel<<<FC, 1024, lds_bytes, stream>>>(ei, base, csr_src, E, N);
    } else {
        // fallback: global-atomic path (reuse Cs/Cd region if present, else overlap xh? —
        // rep arrays fit in the common tail only if ws allows; use cursor+deg region scheme)
        int* rep_out = (int*)Cs;   // may exceed ws if lds_need > ws_size; then reuse u
        int* rep_in  = (int*)Cd;
        if (lds_need > ws_size) {
            rep_out = (int*)u;                       // u unused until agg<0>
            rep_in  = (int*)((char*)u + (size_t)NREP * N * 4);
        }
        hipMemsetAsync(rep_out, 0, (size_t)NREP * N * 4, stream);
        hipMemsetAsync(rep_in, 0, (size_t)NREP * N * 4, stream);
        hipMemsetAsync(cursor, 0, (size_t)N * 4, stream);
        prep_kernel<<<eb, 256, 0, stream>>>(ei, rep_out, rep_in, E, N);
        deg_reduce_rep_kernel<<<(N + 255) / 256, 256, 0, stream>>>(rep_out, rep_in, a_arr,
                                                                   bfac, ab, deg_in, N);
        scanA_kernel<<<G, 1024, 0, stream>>>(deg_in, part, N);
        scanB_kernel<<<1, 64, 0, stream>>>(part, partx, G);
        scanC_kernel<<<G, 1024, 0, stream>>>(deg_in, partx, offs, N);
        fill_kernel<<<eb, 256, 0, stream>>>(ei, offs, cursor, csr_src, E);
    }

    int n4 = N * (D / 4);
    xcvt_kernel<<<(n4 + 255) / 256, 256, 0, stream>>>(x, a_arr, (float2*)xh, n4);

    agg_kernel<0><<<(N + 3) / 4, 256, 0, stream>>>(xh, offs, csr_src, ab, bfac, a_arr,
                                                   u, c_arr, N);
    agg_kernel<1><<<(N + 3) / 4, 256, 0, stream>>>(u, offs, csr_src, ab, bfac, a_arr,
                                                   t2, c_arr, N);
    gemm_final_kernel<<<(N + 31) / 32, 256, 0, stream>>>(t2, wc, bfac, c_arr,
                                                         b + 128, out, N);
}

// Round 4
// 152.117 us; speedup vs baseline: 1.8814x; 1.0503x over previous
//
#include <hip/hip_runtime.h>
#include <hip/hip_fp16.h>

#define D_MODEL 128
#define NREP 8
#define FC 32   // edge-range chunks for LDS histogram / counting sort

// ---------------------------------------------------------------------------
// Edge dtype sniff: first 8 entries as int64 all in [0,2^31) => genuine int64.
// ---------------------------------------------------------------------------
__device__ __forceinline__ bool sniff_i64(const void* ei) {
    const long long* p64 = (const long long*)ei;
    bool f64 = true;
#pragma unroll
    for (int i = 0; i < 8; ++i) {
        long long v = p64[i];
        f64 = f64 && (v >= 0 && v < (1LL << 31));
    }
    return f64;
}

__device__ __forceinline__ void load_edge(const void* ei, int e, int nE, bool f64,
                                          int& s, int& d) {
    if (f64) {
        const long long* p64 = (const long long*)ei;
        s = (int)p64[e];
        d = (int)p64[(size_t)nE + e];
    } else {
        const int* p32 = (const int*)ei;
        s = p32[e];
        d = p32[(size_t)nE + e];
    }
}

// ---------------------------------------------------------------------------
// Packed LDS histogram: one uint32 per node, low16 = src count, high16 = dst.
// grid = FC blocks; block c histograms edge range c. Chunk size <= ~20000
// < 65536 so the 16-bit fields cannot overflow/carry.
// ---------------------------------------------------------------------------
__global__ __launch_bounds__(1024) void hist_kernel(const void* __restrict__ ei,
                                                    unsigned int* __restrict__ Cpk,
                                                    int nE, int n) {
    extern __shared__ unsigned int h[];
    bool f64 = sniff_i64(ei);
    int chunk = blockIdx.x;
    for (int i = threadIdx.x; i < n; i += 1024) h[i] = 0;
    __syncthreads();
    int ech = (nE + FC - 1) / FC;
    int e0 = chunk * ech;
    int e1 = min(nE, e0 + ech);
    if (f64) {
        const long long* p64 = (const long long*)ei;
        for (int e = e0 + threadIdx.x; e < e1; e += 1024) {
            atomicAdd(&h[(int)p64[e]], 1u);
            atomicAdd(&h[(int)p64[(size_t)nE + e]], 0x10000u);
        }
    } else {
        const int* p32 = (const int*)ei;
        for (int e = e0 + threadIdx.x; e < e1; e += 1024) {
            atomicAdd(&h[p32[e]], 1u);
            atomicAdd(&h[p32[(size_t)nE + e]], 0x10000u);
        }
    }
    __syncthreads();
    unsigned int* C = Cpk + (size_t)chunk * n;
    for (int i = threadIdx.x; i < n; i += 1024) C[i] = h[i];
}

// ---------------------------------------------------------------------------
// scanA fused with degree reduction: per node sum packed chunks -> deg_out/in,
// write a/bfac/ab/deg_in, and emit per-block partial sum of deg_in.
// ---------------------------------------------------------------------------
__global__ __launch_bounds__(1024) void scanA_kernel(const unsigned int* __restrict__ Cpk,
                                                     float* __restrict__ a,
                                                     float* __restrict__ bfac,
                                                     float* __restrict__ ab,
                                                     int* __restrict__ deg_in,
                                                     int* __restrict__ part, int n) {
    __shared__ int wsum[16];
    int i = blockIdx.x * 1024 + threadIdx.x;
    int lane = threadIdx.x & 63, wid = threadIdx.x >> 6;
    int din = 0;
    if (i < n) {
        int dout = 0;
#pragma unroll 8
        for (int c = 0; c < FC; ++c) {
            unsigned int w = Cpk[(size_t)c * n + i];
            dout += (int)(w & 0xFFFFu);
            din += (int)(w >> 16);
        }
        float fa = rsqrtf((float)max(dout, 1));
        float fb = rsqrtf((float)max(din, 1));
        a[i] = fa;
        bfac[i] = fb;
        ab[i] = fa * fb;
        deg_in[i] = din;
    }
    int v = din;
#pragma unroll
    for (int d = 32; d > 0; d >>= 1) v += __shfl_down(v, d, 64);
    if (lane == 0) wsum[wid] = v;
    __syncthreads();
    if (threadIdx.x == 0) {
        int s = 0;
#pragma unroll
        for (int w = 0; w < 16; ++w) s += wsum[w];
        part[blockIdx.x] = s;
    }
}

__global__ void scanB_kernel(const int* __restrict__ part, int* __restrict__ partx, int g) {
    if (blockIdx.x == 0 && threadIdx.x == 0) {
        int acc = 0;
        for (int i = 0; i < g; ++i) {
            partx[i] = acc;
            acc += part[i];
        }
    }
}

// ---------------------------------------------------------------------------
// scanC fused with counting-sort base: offs[i] (exclusive) + per-chunk
// absolute cursors base[c][i].
// ---------------------------------------------------------------------------
__global__ __launch_bounds__(1024) void scanC_kernel(const int* __restrict__ deg,
                                                     const int* __restrict__ partx,
                                                     const unsigned int* __restrict__ Cpk,
                                                     int* __restrict__ offs,
                                                     int* __restrict__ base, int n) {
    __shared__ int wsum[16];
    int i = blockIdx.x * 1024 + threadIdx.x;
    int lane = threadIdx.x & 63, wid = threadIdx.x >> 6;
    int v = (i < n) ? deg[i] : 0;
    int s = v;
#pragma unroll
    for (int d = 1; d < 64; d <<= 1) {
        int t = __shfl_up(s, d, 64);
        if (lane >= d) s += t;
    }
    if (lane == 63) wsum[wid] = s;
    __syncthreads();
    if (wid == 0) {
        int wsv = (lane < 16) ? wsum[lane] : 0;
#pragma unroll
        for (int d = 1; d < 16; d <<= 1) {
            int t = __shfl_up(wsv, d, 16);
            if ((lane & 15) >= d) wsv += t;
        }
        if (lane < 16) wsum[lane] = wsv;
    }
    __syncthreads();
    int pfx = partx[blockIdx.x] + ((wid > 0) ? wsum[wid - 1] : 0);
    int incl = pfx + s;
    if (i < n) {
        int run = incl - v;          // exclusive prefix
        offs[i] = run;
        if (i == n - 1) offs[n] = incl;
#pragma unroll 8
        for (int c = 0; c < FC; ++c) {
            base[(size_t)c * n + i] = run;
            run += (int)(Cpk[(size_t)c * n + i] >> 16);
        }
    }
}

// ---------------------------------------------------------------------------
// Counting-sort fill: per-chunk LDS cursors, scattered 4B stores only.
// ---------------------------------------------------------------------------
__global__ __launch_bounds__(1024) void fill_lds_kernel(const void* __restrict__ ei,
                                                        const int* __restrict__ base,
                                                        int* __restrict__ csr_src,
                                                        int nE, int n) {
    extern __shared__ int cur[];
    bool f64 = sniff_i64(ei);
    int chunk = blockIdx.x;
    for (int i = threadIdx.x; i < n; i += 1024) cur[i] = base[(size_t)chunk * n + i];
    __syncthreads();
    int ech = (nE + FC - 1) / FC;
    int e0 = chunk * ech;
    int e1 = min(nE, e0 + ech);
    for (int e = e0 + threadIdx.x; e < e1; e += 1024) {
        int s, d;
        load_edge(ei, e, nE, f64, s, d);
        int slot = atomicAdd(&cur[d], 1);
        csr_src[slot] = s;
    }
}

// ---------------------------------------------------------------------------
// Fallback path (global atomics) — only if N too big for LDS histogram.
// ---------------------------------------------------------------------------
__global__ void prep_kernel(const void* __restrict__ ei, int* __restrict__ rep_out,
                            int* __restrict__ rep_in, int nE, int n) {
    bool f64 = sniff_i64(ei);
    int e = blockIdx.x * blockDim.x + threadIdx.x;
    if (e >= nE) return;
    int s, d;
    load_edge(ei, e, nE, f64, s, d);
    int rep = blockIdx.x & (NREP - 1);
    atomicAdd(&rep_out[(size_t)rep * n + s], 1);
    atomicAdd(&rep_in[(size_t)rep * n + d], 1);
}

__global__ void deg_reduce_rep_kernel(const int* __restrict__ rep_out,
                                      const int* __restrict__ rep_in,
                                      float* __restrict__ a, float* __restrict__ bfac,
                                      float* __restrict__ ab, int* __restrict__ deg_in,
                                      int n) {
    int v = blockIdx.x * blockDim.x + threadIdx.x;
    if (v >= n) return;
    int dout = 0, din = 0;
#pragma unroll
    for (int r = 0; r < NREP; ++r) {
        dout += rep_out[(size_t)r * n + v];
        din += rep_in[(size_t)r * n + v];
    }
    float fa = rsqrtf((float)max(dout, 1));
    float fb = rsqrtf((float)max(din, 1));
    a[v] = fa;
    bfac[v] = fb;
    ab[v] = fa * fb;
    deg_in[v] = din;
}

__global__ __launch_bounds__(1024) void scanA_plain_kernel(const int* __restrict__ deg,
                                                           int* __restrict__ part, int n) {
    __shared__ int wsum[16];
    int i = blockIdx.x * 1024 + threadIdx.x;
    int lane = threadIdx.x & 63, wid = threadIdx.x >> 6;
    int v = (i < n) ? deg[i] : 0;
#pragma unroll
    for (int d = 32; d > 0; d >>= 1) v += __shfl_down(v, d, 64);
    if (lane == 0) wsum[wid] = v;
    __syncthreads();
    if (threadIdx.x == 0) {
        int s = 0;
#pragma unroll
        for (int w = 0; w < 16; ++w) s += wsum[w];
        part[blockIdx.x] = s;
    }
}

__global__ __launch_bounds__(1024) void scanC_plain_kernel(const int* __restrict__ deg,
                                                           const int* __restrict__ partx,
                                                           int* __restrict__ offs, int n) {
    __shared__ int wsum[16];
    int i = blockIdx.x * 1024 + threadIdx.x;
    int lane = threadIdx.x & 63, wid = threadIdx.x >> 6;
    int v = (i < n) ? deg[i] : 0;
    int s = v;
#pragma unroll
    for (int d = 1; d < 64; d <<= 1) {
        int t = __shfl_up(s, d, 64);
        if (lane >= d) s += t;
    }
    if (lane == 63) wsum[wid] = s;
    __syncthreads();
    if (wid == 0) {
        int wsv = (lane < 16) ? wsum[lane] : 0;
#pragma unroll
        for (int d = 1; d < 16; d <<= 1) {
            int t = __shfl_up(wsv, d, 16);
            if ((lane & 15) >= d) wsv += t;
        }
        if (lane < 16) wsum[lane] = wsv;
    }
    __syncthreads();
    int pfx = partx[blockIdx.x] + ((wid > 0) ? wsum[wid - 1] : 0);
    int incl = pfx + s;
    if (i < n) {
        offs[i] = incl - v;
        if (i == n - 1) offs[n] = incl;
    }
}

__global__ void fill_kernel(const void* __restrict__ ei, const int* __restrict__ offs,
                            int* __restrict__ cursor, int* __restrict__ csr_src, int nE) {
    bool f64 = sniff_i64(ei);
    int e = blockIdx.x * blockDim.x + threadIdx.x;
    if (e >= nE) return;
    int s, d;
    load_edge(ei, e, nE, f64, s, d);
    int slot = offs[d] + atomicAdd(&cursor[d], 1);
    csr_src[slot] = s;
}

// ---------------------------------------------------------------------------
// x' = fp16(a[row] * x)
// ---------------------------------------------------------------------------
__global__ void xcvt_kernel(const float* __restrict__ x, const float* __restrict__ a,
                            float2* __restrict__ xh, int n4) {
    int idx = blockIdx.x * blockDim.x + threadIdx.x;
    if (idx >= n4) return;
    int row = idx >> 5;   // 32 float4 per row
    float s = a[row];
    float4 v = ((const float4*)x)[idx];
    union { __half2 h2[2]; float2 f2; } u;
    u.h2[0] = __floats2half2_rn(s * v.x, s * v.y);
    u.h2[1] = __floats2half2_rn(s * v.z, s * v.w);
    xh[idx] = u.f2;
}

// ---------------------------------------------------------------------------
// Gather-sum over fp16 rows, one wave per dst node, lane owns half2.
// Unrolled x4 for memory-level parallelism (gather is latency-bound:
// VALUBusy ~5%, effective L2-miss BW 2.8 TB/s << L3 capability).
// MODE 0: out = fp16(ab[v]*sum). MODE 1: out = fp16(sum), c[v]=bfac*sum(a[src]).
// ---------------------------------------------------------------------------
template <int MODE>
__global__ __launch_bounds__(256) void agg_kernel(const __half2* __restrict__ rows_in,
                                                  const int* __restrict__ offs,
                                                  const int* __restrict__ csr,
                                                  const float* __restrict__ ab,
                                                  const float* __restrict__ bfac,
                                                  const float* __restrict__ a_arr,
                                                  __half2* __restrict__ out_rows,
                                                  float* __restrict__ c_out, int n) {
    int node = blockIdx.x * 4 + (threadIdx.x >> 6);
    if (node >= n) return;
    node = __builtin_amdgcn_readfirstlane(node);  // wave-uniform -> scalar loads
    int lane = threadIdx.x & 63;
    int beg = offs[node], end = offs[node + 1];
    float ax0 = 0.f, ay0 = 0.f, ax1 = 0.f, ay1 = 0.f;
    float ax2 = 0.f, ay2 = 0.f, ax3 = 0.f, ay3 = 0.f;
    float cs = 0.f;
    int e = beg;
    for (; e + 3 < end; e += 4) {
        int s0 = csr[e], s1 = csr[e + 1], s2 = csr[e + 2], s3 = csr[e + 3];
        __half2 v0 = rows_in[(size_t)s0 * 64 + lane];
        __half2 v1 = rows_in[(size_t)s1 * 64 + lane];
        __half2 v2 = rows_in[(size_t)s2 * 64 + lane];
        __half2 v3 = rows_in[(size_t)s3 * 64 + lane];
        float2 f0 = __half22float2(v0);
        float2 f1 = __half22float2(v1);
        float2 f2 = __half22float2(v2);
        float2 f3 = __half22float2(v3);
        ax0 += f0.x; ay0 += f0.y;
        ax1 += f1.x; ay1 += f1.y;
        ax2 += f2.x; ay2 += f2.y;
        ax3 += f3.x; ay3 += f3.y;
        if (MODE == 1) cs += (a_arr[s0] + a_arr[s1]) + (a_arr[s2] + a_arr[s3]);
    }
    for (; e < end; ++e) {
        int s0 = csr[e];
        __half2 v0 = rows_in[(size_t)s0 * 64 + lane];
        float2 f0 = __half22float2(v0);
        ax0 += f0.x; ay0 += f0.y;
        if (MODE == 1) cs += a_arr[s0];
    }
    float sx = (ax0 + ax1) + (ax2 + ax3);
    float sy = (ay0 + ay1) + (ay2 + ay3);
    if (MODE == 0) {
        float sc = ab[node];
        out_rows[(size_t)node * 64 + lane] = __floats2half2_rn(sc * sx, sc * sy);
    } else {
        out_rows[(size_t)node * 64 + lane] = __floats2half2_rn(sx, sy);
        if (lane == 0) c_out[node] = bfac[node] * cs;
    }
}

// ---------------------------------------------------------------------------
// Combined weights: wc[0..127][128] = W1@W2 ; wc[128][:] = b1@W2
// ---------------------------------------------------------------------------
__global__ void wc_kernel(const float* __restrict__ W, const float* __restrict__ b,
                          float* __restrict__ wc) {
    int gid = blockIdx.x * blockDim.x + threadIdx.x;
    if (gid >= 129 * 128) return;
    int r = gid >> 7, j = gid & 127;
    const float* W2 = W + 128 * 128;
    float acc = 0.f;
    if (r < 128) {
        const float* w1r = W + (size_t)r * 128;
#pragma unroll 4
        for (int k = 0; k < 128; ++k) acc = fmaf(w1r[k], W2[(size_t)k * 128 + j], acc);
    } else {
#pragma unroll 4
        for (int k = 0; k < 128; ++k) acc = fmaf(b[k], W2[(size_t)k * 128 + j], acc);
    }
    wc[gid] = acc;
}

// ---------------------------------------------------------------------------
// Final GEMM + epilogue: out = bfac[row]*(t2raw @ Wc) + c[row]*g + b2
// ---------------------------------------------------------------------------
__global__ __launch_bounds__(256) void gemm_final_kernel(const __half2* __restrict__ A2,
                                                         const float* __restrict__ wc,
                                                         const float* __restrict__ bfac,
                                                         const float* __restrict__ c_arr,
                                                         const float* __restrict__ b2,
                                                         float* __restrict__ out, int nRows) {
    __shared__ float Ws[32][128];
    __shared__ float At[32][36];
    int tid = threadIdx.x;
    int tc = tid & 31;
    int tr = tid >> 5;
    int row0 = blockIdx.x * 32;
    float acc[4][4] = {};

    for (int k0 = 0; k0 < D_MODEL; k0 += 32) {
        __syncthreads();
        {
            const float4* Wg = (const float4*)(wc + (size_t)k0 * D_MODEL);
            float4* WsV = (float4*)&Ws[0][0];
#pragma unroll
            for (int i = 0; i < 4; ++i) WsV[tid + 256 * i] = Wg[tid + 256 * i];
        }
        int k0h = k0 >> 1;
#pragma unroll
        for (int i = 0; i < 2; ++i) {
            int lin = tid + 256 * i;      // 0..511
            int r = lin >> 4;             // 0..31
            int h = lin & 15;
            int row = row0 + r;
            __half2 v = (row < nRows) ? A2[(size_t)row * 64 + k0h + h]
                                      : __floats2half2_rn(0.f, 0.f);
            float2 f = __half22float2(v);
            At[2 * h][r] = f.x;
            At[2 * h + 1][r] = f.y;
        }
        __syncthreads();
#pragma unroll
        for (int kk = 0; kk < 32; ++kk) {
            float4 w4 = *(const float4*)&Ws[kk][4 * tc];
            float4 a4 = *(const float4*)&At[kk][4 * tr];
            float wv[4] = {w4.x, w4.y, w4.z, w4.w};
            float av[4] = {a4.x, a4.y, a4.z, a4.w};
#pragma unroll
            for (int i = 0; i < 4; ++i)
#pragma unroll
                for (int j = 0; j < 4; ++j)
                    acc[i][j] = fmaf(av[i], wv[j], acc[i][j]);
        }
    }
    float4 g4 = *(const float4*)(wc + 128 * 128 + 4 * tc);
    float4 b4 = *(const float4*)(b2 + 4 * tc);
#pragma unroll
    for (int i = 0; i < 4; ++i) {
        int row = row0 + 4 * tr + i;
        if (row < nRows) {
            float bf = bfac[row];
            float cv = c_arr[row];
            float4 o;
            o.x = bf * acc[i][0] + cv * g4.x + b4.x;
            o.y = bf * acc[i][1] + cv * g4.y + b4.y;
            o.z = bf * acc[i][2] + cv * g4.z + b4.z;
            o.w = bf * acc[i][3] + cv * g4.w + b4.w;
            *(float4*)(out + (size_t)row * D_MODEL + 4 * tc) = o;
        }
    }
}

// ---------------------------------------------------------------------------
extern "C" void kernel_launch(void* const* d_in, const int* in_sizes, int n_in,
                              void* d_out, int out_size, void* d_ws, size_t ws_size,
                              hipStream_t stream) {
    const float* x = (const float*)d_in[0];
    const float* W = (const float*)d_in[1];
    const float* b = (const float*)d_in[2];
    const void* ei = d_in[3];
    const int D = D_MODEL;
    int N = in_sizes[0] / D;
    int E = in_sizes[3] / 2;
    float* out = (float*)d_out;

    char* p = (char*)d_ws;
    size_t off = 0;
    auto take = [&](size_t bytes) {
        void* r = p + off;
        off += (bytes + 255) & ~(size_t)255;
        return r;
    };
    __half2* xh   = (__half2*)take((size_t)N * D * 2);
    __half2* u    = (__half2*)take((size_t)N * D * 2);
    int* csr_src  = (int*)take((size_t)E * 4);
    float* a_arr  = (float*)take((size_t)N * 4);
    float* bfac   = (float*)take((size_t)N * 4);
    float* ab     = (float*)take((size_t)N * 4);
    float* c_arr  = (float*)take((size_t)N * 4);
    int* deg_in   = (int*)take((size_t)N * 4);
    int* offs     = (int*)take((size_t)(N + 1) * 4);
    int* cursor   = (int*)take((size_t)N * 4);
    int* part     = (int*)take(256 * 4);
    int* partx    = (int*)take(256 * 4);
    float* wc     = (float*)take((size_t)129 * 128 * 4);
    unsigned int* Cpk = (unsigned int*)take((size_t)FC * N * 4);
    int* base     = (int*)take((size_t)FC * N * 4);
    size_t lds_need = off;
    __half2* t2 = xh;   // alias: x_half dead once agg<0> completes

    size_t lds_bytes = (size_t)N * 4;
    bool use_lds = (lds_bytes <= 160000) && (lds_need <= ws_size);

    int eb = (E + 255) / 256;
    int G = (N + 1023) / 1024;

    wc_kernel<<<(129 * 128 + 255) / 256, 256, 0, stream>>>(W, b, wc);

    if (use_lds) {
        hist_kernel<<<FC, 1024, lds_bytes, stream>>>(ei, Cpk, E, N);
        scanA_kernel<<<G, 1024, 0, stream>>>(Cpk, a_arr, bfac, ab, deg_in, part, N);
        scanB_kernel<<<1, 64, 0, stream>>>(part, partx, G);
        scanC_kernel<<<G, 1024, 0, stream>>>(deg_in, partx, Cpk, offs, base, N);
        fill_lds_kernel<<<FC, 1024, lds_bytes, stream>>>(ei, base, csr_src, E, N);
    } else {
        int* rep_out = (int*)Cpk;
        int* rep_in  = (int*)base;
        if (lds_need > ws_size) {
            rep_out = (int*)u;
            rep_in  = (int*)((char*)u + (size_t)NREP * N * 4);
        }
        hipMemsetAsync(rep_out, 0, (size_t)NREP * N * 4, stream);
        hipMemsetAsync(rep_in, 0, (size_t)NREP * N * 4, stream);
        hipMemsetAsync(cursor, 0, (size_t)N * 4, stream);
        prep_kernel<<<eb, 256, 0, stream>>>(ei, rep_out, rep_in, E, N);
        deg_reduce_rep_kernel<<<(N + 255) / 256, 256, 0, stream>>>(rep_out, rep_in, a_arr,
                                                                   bfac, ab, deg_in, N);
        scanA_plain_kernel<<<G, 1024, 0, stream>>>(deg_in, part, N);
        scanB_kernel<<<1, 64, 0, stream>>>(part, partx, G);
        scanC_plain_kernel<<<G, 1024, 0, stream>>>(deg_in, partx, offs, N);
        fill_kernel<<<eb, 256, 0, stream>>>(ei, offs, cursor, csr_src, E);
    }

    int n4 = N * (D / 4);
    xcvt_kernel<<<(n4 + 255) / 256, 256, 0, stream>>>(x, a_arr, (float2*)xh, n4);

    agg_kernel<0><<<(N + 3) / 4, 256, 0, stream>>>(xh, offs, csr_src, ab, bfac, a_arr,
                                                   u, c_arr, N);
    agg_kernel<1><<<(N + 3) / 4, 256, 0, stream>>>(u, offs, csr_src, ab, bfac, a_arr,
                                                   t2, c_arr, N);
    gemm_final_kernel<<<(N + 31) / 32, 256, 0, stream>>>(t2, wc, bfac, c_arr,
                                                         b + 128, out, N);
}